// Round 1
// baseline (3329.109 us; speedup 1.0000x reference)
//
#include <hip/hip_runtime.h>
#include <math.h>

#define HH 256
#define WW 512
#define CC 768
#define KW 129            // kept W modes (0..128)
#define NB 8
#define BS 96
#define MPC (KW*HH)       // modes per channel = 33024

constexpr float SF = 0.00276213586400528f;   // 1/sqrt(131072)  forward ortho
constexpr float SI = 0.00552427172801056f;   // 2/sqrt(131072)  inverse ortho (x2 from packing)
constexpr float LAM = 0.01f;

// ---------------------------------------------------------------------------
// 256-point Stockham radix-2 FFT in LDS (ping-pong s0<->s1, 8 stages, result in s0).
// sign = -1 forward, +1 inverse (unnormalized). nthr threads per row, all block
// threads must call this together (uniform control flow; __syncthreads inside).
// ---------------------------------------------------------------------------
__device__ inline void fft256(float2* s0, float2* s1, int lane, int nthr, float sign) {
    float2* src = s0;
    float2* dst = s1;
    int logls = 0;
    for (int n = 256; n >= 2; n >>= 1) {
        int m = n >> 1;
        int ls = 1 << logls;
        float fac = sign * 6.283185307179586f / (float)n;
        for (int t = lane; t < 128; t += nthr) {
            int q = t & (ls - 1);
            int p = t >> logls;
            float2 a = src[q + (p << logls)];
            float2 b = src[q + ((p + m) << logls)];
            float sn, cs;
            __sincosf(fac * (float)p, &sn, &cs);
            float2 dif = make_float2(a.x - b.x, a.y - b.y);
            dst[q + (p << (logls + 1))] = make_float2(a.x + b.x, a.y + b.y);
            dst[q + ((2 * p + 1) << logls)] =
                make_float2(dif.x * cs - dif.y * sn, dif.x * sn + dif.y * cs);
        }
        __syncthreads();
        float2* tmp = src; src = dst; dst = tmp;
        logls++;
    }
}

// ---------------------------------------------------------------------------
// K1: forward real FFT along W (512 real -> 129 complex), packed-real trick.
// 8 rows (same channel, consecutive h) per block; LDS tile-transpose so the
// output A[c][k][h] (h contiguous) is written in 64B chunks.
// ---------------------------------------------------------------------------
__global__ __launch_bounds__(512) void k1_rfftw(const float* __restrict__ x,
                                                float2* __restrict__ A) {
    __shared__ float2 b0[8][256];
    __shared__ float2 b1[8][256];
    __shared__ float2 tile[KW * 8];

    int tid = threadIdx.x;
    int r = tid >> 6;            // row 0..7
    int lane = tid & 63;
    int blk = blockIdx.x;        // 0..24575
    int c = blk >> 5;            // channel
    int h0 = (blk & 31) << 3;    // first h of this block
    int h = h0 + r;

    const float2* xrow = (const float2*)(x + ((size_t)c * HH + h) * WW);
    float2* s0 = b0[r];
    float2* s1 = b1[r];

    // pack: z[n] = x[2n] + i x[2n+1], scaled by forward ortho factor
    for (int n = lane; n < 256; n += 64) {
        float2 v = xrow[n];
        s0[n] = make_float2(v.x * SF, v.y * SF);
    }
    __syncthreads();

    fft256(s0, s1, lane, 64, -1.0f);   // result in s0

    // combine to X[k], k = 0..128
    for (int k = lane; k <= 128; k += 64) {
        float2 Za = s0[k & 255];
        float2 Zb = s0[(256 - k) & 255];
        // Xe = 0.5(Za + conj(Zb)); Xo = -0.5i(Za - conj(Zb))
        float2 Xe = make_float2(0.5f * (Za.x + Zb.x), 0.5f * (Za.y - Zb.y));
        float dx = Za.x - Zb.x;
        float dy = Za.y + Zb.y;
        float2 Xo = make_float2(0.5f * dy, -0.5f * dx);
        float sn, cs;
        __sincosf(-6.283185307179586f * (float)k / 512.0f, &sn, &cs);
        float2 X;
        X.x = Xe.x + (Xo.x * cs - Xo.y * sn);
        X.y = Xe.y + (Xo.x * sn + Xo.y * cs);
        tile[k * 8 + r] = X;
    }
    __syncthreads();

    for (int idx = tid; idx < KW * 8; idx += 512) {
        int k = idx >> 3;
        int r2 = idx & 7;
        A[((size_t)c * KW + k) * HH + h0 + r2] = tile[idx];
    }
}

// ---------------------------------------------------------------------------
// K2/K4: 256-pt complex FFT along H, in place. A flat = [c][k][h], so each
// column is 256 contiguous float2. 2 columns per 256-thread block.
// SIGN = -1 forward, +1 inverse (unnormalized).
// ---------------------------------------------------------------------------
template <int SIGN>
__global__ __launch_bounds__(256) void k_colfft(float2* __restrict__ A) {
    __shared__ float2 b0[2][256];
    __shared__ float2 b1[2][256];
    int tid = threadIdx.x;
    int col = tid >> 7;          // 0..1
    int lane = tid & 127;
    size_t base = ((size_t)blockIdx.x * 2 + col) * 256;
    float2* s0 = b0[col];
    float2* s1 = b1[col];
    for (int n = lane; n < 256; n += 128) s0[n] = A[base + n];
    __syncthreads();
    fft256(s0, s1, lane, 128, (float)SIGN);
    for (int n = lane; n < 256; n += 128) A[base + n] = s0[n];
}

// ---------------------------------------------------------------------------
// K3: per-mode complex MLP, in place on A. One block = one channel-block k
// and a tile of 32 modes; a-tile (96x32) and hidden (96x32) staged in LDS;
// weights streamed from global (L1/L2 resident, broadcast across lanes).
// ---------------------------------------------------------------------------
__global__ __launch_bounds__(256) void k3_mlp(float2* __restrict__ A,
                                              const float2* __restrict__ w1,
                                              const float2* __restrict__ b1,
                                              const float2* __restrict__ w2,
                                              const float2* __restrict__ b2) {
    __shared__ float2 atile[BS][32];
    __shared__ float2 htile[BS][32];
    int tid = threadIdx.x;
    int bk = blockIdx.x / (MPC / 32);          // 0..7
    int m0 = (blockIdx.x % (MPC / 32)) * 32;

    for (int idx = tid; idx < BS * 32; idx += 256) {
        int i = idx >> 5;
        int t = idx & 31;
        atile[i][t] = A[((size_t)(bk * BS + i)) * MPC + m0 + t];
    }
    __syncthreads();

    int osub = tid >> 5;   // 0..7
    int t = tid & 31;
    const float2* w1b = w1 + (size_t)bk * BS * BS;
    const float2* b1b = b1 + (size_t)bk * BS;
    const float2* w2b = w2 + (size_t)bk * BS * BS;
    const float2* b2b = b2 + (size_t)bk * BS;

    for (int rr = 0; rr < 12; rr++) {
        int o = rr * 8 + osub;
        float2 acc = b1b[o];
#pragma unroll 8
        for (int i = 0; i < BS; i++) {
            float2 w = w1b[i * BS + o];
            float2 a = atile[i][t];
            acc.x = fmaf(a.x, w.x, fmaf(-a.y, w.y, acc.x));
            acc.y = fmaf(a.x, w.y, fmaf(a.y, w.x, acc.y));
        }
        htile[o][t] = make_float2(fmaxf(acc.x, 0.f), fmaxf(acc.y, 0.f));
    }
    __syncthreads();

    for (int rr = 0; rr < 12; rr++) {
        int o = rr * 8 + osub;
        float2 acc = b2b[o];
#pragma unroll 8
        for (int i = 0; i < BS; i++) {
            float2 w = w2b[i * BS + o];
            float2 a = htile[i][t];
            acc.x = fmaf(a.x, w.x, fmaf(-a.y, w.y, acc.x));
            acc.y = fmaf(a.x, w.y, fmaf(a.y, w.x, acc.y));
        }
        float rx = fmaxf(fabsf(acc.x) - LAM, 0.f);
        float ry = fmaxf(fabsf(acc.y) - LAM, 0.f);
        acc.x = copysignf(rx, acc.x);
        acc.y = copysignf(ry, acc.y);
        A[((size_t)(bk * BS + o)) * MPC + m0 + t] = acc;
    }
}

// ---------------------------------------------------------------------------
// K5: inverse real FFT along W (129 complex modes, rest zero -> 512 real),
// packed-real trick, fused + x bias, final ortho scale. 8 rows per block;
// LDS tile gathers the strided A[c][k][h0..h0+7] reads in 64B chunks.
// Matches numpy irfft: imaginary part of DC bin is ignored (zeroed).
// ---------------------------------------------------------------------------
__global__ __launch_bounds__(512) void k5_irfftw(const float2* __restrict__ A,
                                                 const float* __restrict__ x,
                                                 float* __restrict__ out) {
    __shared__ float2 b0[8][256];
    __shared__ float2 b1[8][256];
    __shared__ float2 tile[KW * 8];

    int tid = threadIdx.x;
    int blk = blockIdx.x;
    int c = blk >> 5;
    int h0 = (blk & 31) << 3;

    for (int idx = tid; idx < KW * 8; idx += 512) {
        int k = idx >> 3;
        int r2 = idx & 7;
        tile[idx] = A[((size_t)c * KW + k) * HH + h0 + r2];
    }
    __syncthreads();

    int r = tid >> 6;
    int lane = tid & 63;
    int h = h0 + r;
    float2* s0 = b0[r];
    float2* s1 = b1[r];

    // Zhat[k] = Xe[k] + i*Xo[k], k = 0..255
    for (int k = lane; k < 256; k += 64) {
        float2 P = make_float2(0.f, 0.f);
        float2 Q = make_float2(0.f, 0.f);
        if (k <= 128) {
            P = tile[k * 8 + r];
            if (k == 0) P.y = 0.f;            // numpy irfft drops Im(DC)
        }
        if (k >= 128) {                        // X[k+256] = conj(X[256-k]), nonzero iff 256-k<=128
            float2 q = tile[(256 - k) * 8 + r];
            Q = make_float2(q.x, -q.y);
        }
        float2 Xe = make_float2(0.5f * (P.x + Q.x), 0.5f * (P.y + Q.y));
        float dx = P.x - Q.x;
        float dy = P.y - Q.y;
        float sn, cs;
        __sincosf(6.283185307179586f * (float)k / 512.0f, &sn, &cs);
        float2 Xo = make_float2(0.5f * (dx * cs - dy * sn), 0.5f * (dx * sn + dy * cs));
        s0[k] = make_float2(Xe.x - Xo.y, Xe.y + Xo.x);
    }
    __syncthreads();

    fft256(s0, s1, lane, 64, 1.0f);   // unnormalized inverse, result in s0

    const float2* xr = (const float2*)(x + ((size_t)c * HH + h) * WW);
    float2* orow = (float2*)(out + ((size_t)c * HH + h) * WW);
    for (int m = lane; m < 256; m += 64) {
        float2 z = s0[m];
        float2 xv = xr[m];
        orow[m] = make_float2(fmaf(SI, z.x, xv.x), fmaf(SI, z.y, xv.y));
    }
}

// ---------------------------------------------------------------------------
extern "C" void kernel_launch(void* const* d_in, const int* in_sizes, int n_in,
                              void* d_out, int out_size, void* d_ws, size_t ws_size,
                              hipStream_t stream) {
    const float* x = (const float*)d_in[0];
    const float2* w1 = (const float2*)d_in[1];
    const float2* b1 = (const float2*)d_in[2];
    const float2* w2 = (const float2*)d_in[3];
    const float2* b2 = (const float2*)d_in[4];
    float* out = (float*)d_out;
    float2* A = (float2*)d_ws;   // [768][129][256] complex = 202,899,456 bytes

    k1_rfftw<<<dim3(CC * HH / 8), dim3(512), 0, stream>>>(x, A);
    k_colfft<-1><<<dim3(CC * KW / 2), dim3(256), 0, stream>>>(A);
    k3_mlp<<<dim3(NB * (MPC / 32)), dim3(256), 0, stream>>>(A, w1, b1, w2, b2);
    k_colfft<1><<<dim3(CC * KW / 2), dim3(256), 0, stream>>>(A);
    k5_irfftw<<<dim3(CC * HH / 8), dim3(512), 0, stream>>>(A, x, out);
}